// Round 2
// baseline (354.617 us; speedup 1.0000x reference)
//
#include <hip/hip_runtime.h>
#include <math.h>

#define BB 16
#define CC 64
#define HH 256
#define WW 256
#define HWX (HH * WW)          // 65536 pixels per image per channel
#define NPIX (BB * HWX)        // 1,048,576 total output pixels
#define TR 16                  // output rows per block
#define SR (TR + 2)            // staged rows incl. 1-row halo each side

typedef float f4 __attribute__((ext_vector_type(4)));

// Fused kernel: 1x1 conv + exp + 3x3 replicate-pad box-sum + divide.
// No workspace. 256 blocks = 16 images x 16 row-tiles (16 rows each).
// Each block: conv 18 rows (2 halo, row-clamped) of 256 cols.
//   - e0 (exp of channel 0) stays in registers (f4 per pass, static index)
//   - s = e0+e1 staged in LDS [18][256] = 18 KB
//   - one barrier, then box-sum from LDS + divide + NT store of 16 rows.
// Halo recompute costs +12.5% x reads but kills the 8 MB intermediate
// round-trip, the second launch, and all d_ws use.
__global__ __launch_bounds__(256) void fused_kernel(
    const float* __restrict__ x,
    const float* __restrict__ Wt,     // [2,64]
    const float* __restrict__ bias,   // [2]
    float* __restrict__ out)
{
    __shared__ float w0[CC];
    __shared__ float w1[CC];
    __shared__ float s_lds[SR][WW];   // 18 KB

    const int tid = threadIdx.x;
    if (tid < CC) {
        w0[tid] = Wt[tid];        // W[0][c]
        w1[tid] = Wt[CC + tid];   // W[1][c]
    }
    __syncthreads();

    const float b0 = bias[0];
    const float b1 = bias[1];

    const int blk  = blockIdx.x;      // 0..255
    const int bimg = blk >> 4;        // image index (16 tiles per image)
    const int tile = blk & 15;
    const int r0   = tile * TR;       // first output row of this tile

    const int lane = tid & 63;
    const int wid  = tid >> 6;        // wave id 0..3 (row within a pass)
    const int w    = lane << 2;       // first column of this thread's f4

    const float* xb = x + (long long)bimg * CC * HWX;

    f4 e0reg[5];                      // statically indexed (full unroll)

    // ---- conv phase: 5 passes cover staged rows 0..17 ----
    // pass p<4: lr = 4p+wid (rows 0..15); pass 4: lr = 16+wid, wid<2 only.
    #pragma unroll
    for (int p = 0; p < 5; ++p) {
        const int lr = (p < 4) ? (4 * p + wid) : (16 + wid);
        const bool active = (p < 4) || (wid < 2);
        if (active) {
            const int rr = r0 - 1 + lr;                 // logical row (may be -1/256)
            const int rc = min(max(rr, 0), HH - 1);     // replicate clamp
            const float* xp = xb + rc * WW + w;
            f4 a0 = {b0, b0, b0, b0};
            f4 a1 = {b1, b1, b1, b1};
            #pragma unroll 8
            for (int c = 0; c < CC; ++c) {
                const f4 v = __builtin_nontemporal_load((const f4*)(xp + (long long)c * HWX));
                const float wc0 = w0[c];
                const float wc1 = w1[c];
                a0[0] = fmaf(v[0], wc0, a0[0]);
                a0[1] = fmaf(v[1], wc0, a0[1]);
                a0[2] = fmaf(v[2], wc0, a0[2]);
                a0[3] = fmaf(v[3], wc0, a0[3]);
                a1[0] = fmaf(v[0], wc1, a1[0]);
                a1[1] = fmaf(v[1], wc1, a1[1]);
                a1[2] = fmaf(v[2], wc1, a1[2]);
                a1[3] = fmaf(v[3], wc1, a1[3]);
            }
            f4 E0, E1;
            E0[0] = __expf(a0[0]); E0[1] = __expf(a0[1]);
            E0[2] = __expf(a0[2]); E0[3] = __expf(a0[3]);
            E1[0] = __expf(a1[0]); E1[1] = __expf(a1[1]);
            E1[2] = __expf(a1[2]); E1[3] = __expf(a1[3]);
            e0reg[p] = E0;
            *(f4*)&s_lds[lr][w] = E0 + E1;
        }
    }
    __syncthreads();

    // ---- box + divide phase: each thread outputs its 4 computed rows ----
    float* ob = out + (long long)bimg * HWX;
    const int wl = (w > 0)    ? w - 1 : 0;       // clamped left col
    const int wr = (lane < 63) ? w + 4 : WW - 1; // clamped right col

    #pragma unroll
    for (int p = 0; p < 5; ++p) {
        const int lr = (p < 4) ? (4 * p + wid) : (16 + wid);
        // output iff this thread computed the row AND it's a non-halo row
        const bool isout = (p < 4) ? (lr >= 1) : (wid == 0);
        if (isout) {
            const int rr = r0 - 1 + lr;          // in [r0, r0+15]
            const float* rm = s_lds[lr - 1];
            const float* rc = s_lds[lr];
            const float* rp = s_lds[lr + 1];
            const f4 V = *(const f4*)(rm + w) + *(const f4*)(rc + w) + *(const f4*)(rp + w);
            const float L = rm[wl] + rc[wl] + rp[wl];
            const float R = rm[wr] + rc[wr] + rp[wr];
            const f4 E = e0reg[p];
            f4 o;
            o[0] = E[0] / (L    + V[0] + V[1]);
            o[1] = E[1] / (V[0] + V[1] + V[2]);
            o[2] = E[2] / (V[1] + V[2] + V[3]);
            o[3] = E[3] / (V[2] + V[3] + R);
            __builtin_nontemporal_store(o, (f4*)(ob + rr * WW + w));
        }
    }
}

extern "C" void kernel_launch(void* const* d_in, const int* in_sizes, int n_in,
                              void* d_out, int out_size, void* d_ws, size_t ws_size,
                              hipStream_t stream) {
    const float* x    = (const float*)d_in[0];
    const float* Wt   = (const float*)d_in[1];
    const float* bias = (const float*)d_in[2];
    float* out = (float*)d_out;
    (void)d_ws; (void)ws_size;   // workspace intentionally unused

    const int threads = 256;
    const int blocks  = BB * (HH / TR);   // 256
    fused_kernel<<<blocks, threads, 0, stream>>>(x, Wt, bias, out);
}

// Round 3
// 342.894 us; speedup vs baseline: 1.0342x; 1.0342x over previous
//
#include <hip/hip_runtime.h>
#include <math.h>

#define BB 16
#define CC 64
#define HH 256
#define WW 256
#define HWX (HH * WW)          // 65536 pixels per image per channel
#define NPIX (BB * HWX)        // 1,048,576 total output pixels

typedef float f4 __attribute__((ext_vector_type(4)));

// Kernel 1: 1x1 conv (channel contraction) + exp. Each thread computes 4
// consecutive pixels (float4 loads = 16B/lane coalescing sweet spot).
// x is 268 MB streamed once -> non-temporal loads so it doesn't evict the
// just-written e0/s (8 MB) from L2 before kernel 2 reads them.
// 1024 blocks x 256 thr = 16 waves/CU; 8-deep unrolled NT loads keep
// ~128 KB/CU in flight -> BW-saturated (floor: 268 MB / 6.3 TB/s = 43 us).
__global__ __launch_bounds__(256) void conv_exp_kernel(
    const float* __restrict__ x,
    const float* __restrict__ Wt,     // [2,64]
    const float* __restrict__ bias,   // [2]
    float* __restrict__ e0,
    float* __restrict__ s)
{
    __shared__ float w0[CC];
    __shared__ float w1[CC];
    const int tid = threadIdx.x;
    if (tid < CC) {
        w0[tid] = Wt[tid];        // W[0][c]
        w1[tid] = Wt[CC + tid];   // W[1][c]
    }
    __syncthreads();

    const float b0 = bias[0];
    const float b1 = bias[1];

    const long long p4 = (long long)blockIdx.x * blockDim.x + tid;
    const long long base = p4 * 4;            // first pixel index
    if (base >= NPIX) return;
    const int bimg = (int)(base >> 16);       // / 65536
    const int q    = (int)(base & 65535);     // within-image pixel offset
    const float* xp = x + (long long)bimg * CC * HWX + q;

    f4 a0 = {b0, b0, b0, b0};
    f4 a1 = {b1, b1, b1, b1};

    #pragma unroll 8
    for (int c = 0; c < CC; ++c) {
        const f4 v = __builtin_nontemporal_load((const f4*)(xp + (long long)c * HWX));
        const float wc0 = w0[c];
        const float wc1 = w1[c];
        a0[0] = fmaf(v[0], wc0, a0[0]);
        a0[1] = fmaf(v[1], wc0, a0[1]);
        a0[2] = fmaf(v[2], wc0, a0[2]);
        a0[3] = fmaf(v[3], wc0, a0[3]);
        a1[0] = fmaf(v[0], wc1, a1[0]);
        a1[1] = fmaf(v[1], wc1, a1[1]);
        a1[2] = fmaf(v[2], wc1, a1[2]);
        a1[3] = fmaf(v[3], wc1, a1[3]);
    }

    f4 E0, E1, S;
    E0[0] = __expf(a0[0]); E0[1] = __expf(a0[1]); E0[2] = __expf(a0[2]); E0[3] = __expf(a0[3]);
    E1[0] = __expf(a1[0]); E1[1] = __expf(a1[1]); E1[2] = __expf(a1[2]); E1[3] = __expf(a1[3]);
    S = E0 + E1;

    *(f4*)(e0 + base) = E0;   // regular stores: keep L2-resident for kernel 2
    *(f4*)(s  + base) = S;
}

// Kernel 2: 3x3 edge-clamped box sum over s, then out = e0 / boxsum.
// Vectorized: 4 pixels/thread. Per thread: 3 vertical float4 loads (rows
// h-1,h,h+1 summed first), 6 clamped edge scalars, 1 float4 e0 load,
// 1 non-temporal float4 store -> 10 loads + 1 store per 4 px.
// Same 1024-block grid as k1 -> block i maps to the same XCD under
// round-robin dispatch -> e0/s reads are L2-local.
__global__ __launch_bounds__(256) void box_div_kernel(
    const float* __restrict__ e0,
    const float* __restrict__ s,
    float* __restrict__ out)
{
    const int t4 = blockIdx.x * blockDim.x + threadIdx.x;  // 0 .. NPIX/4-1
    if (t4 >= NPIX / 4) return;
    const int w4   = t4 & 63;          // which float4 along W
    const int w    = w4 << 2;          // first column of this thread
    const int hq   = t4 >> 6;          // global row index (B*H rows)
    const int h    = hq & 255;
    const int bimg = hq >> 8;

    const int hm = (h > 0)       ? h - 1 : 0;
    const int hp = (h < HH - 1)  ? h + 1 : HH - 1;

    const float* sb  = s + (long long)bimg * HWX;
    const float* rmp = sb + hm * WW;
    const float* r0p = sb + h  * WW;
    const float* rpp = sb + hp * WW;

    // vertical sum of the 3 rows, aligned float4 at columns w..w+3
    const f4 V = *(const f4*)(rmp + w) + *(const f4*)(r0p + w) + *(const f4*)(rpp + w);

    // clamped edge columns w-1 and w+4 (replicate pad)
    const int wl = (w > 0)       ? w - 1 : 0;
    const int wr = (w4 < 63)     ? w + 4 : WW - 1;
    const float L = rmp[wl] + r0p[wl] + rpp[wl];
    const float R = rmp[wr] + r0p[wr] + rpp[wr];

    const f4 E = __builtin_nontemporal_load((const f4*)(e0 + (long long)t4 * 4));

    f4 o;
    o[0] = E[0] / (L    + V[0] + V[1]);
    o[1] = E[1] / (V[0] + V[1] + V[2]);
    o[2] = E[2] / (V[1] + V[2] + V[3]);
    o[3] = E[3] / (V[2] + V[3] + R);

    __builtin_nontemporal_store(o, (f4*)(out + (long long)t4 * 4));
}

extern "C" void kernel_launch(void* const* d_in, const int* in_sizes, int n_in,
                              void* d_out, int out_size, void* d_ws, size_t ws_size,
                              hipStream_t stream) {
    const float* x    = (const float*)d_in[0];
    const float* Wt   = (const float*)d_in[1];
    const float* bias = (const float*)d_in[2];
    float* out = (float*)d_out;

    float* e0 = (float*)d_ws;          // NPIX floats = 4 MiB
    float* s  = e0 + NPIX;             // NPIX floats = 4 MiB

    // Kernel 1: NPIX/4 threads
    {
        const int threads = 256;
        const int total = NPIX / 4;    // 262,144
        const int blocks = (total + threads - 1) / threads;  // 1024
        conv_exp_kernel<<<blocks, threads, 0, stream>>>(x, Wt, bias, e0, s);
    }
    // Kernel 2: NPIX/4 threads (4 px each)
    {
        const int threads = 256;
        const int total = NPIX / 4;    // 262,144
        const int blocks = (total + threads - 1) / threads;   // 1024
        box_div_kernel<<<blocks, threads, 0, stream>>>(e0, s, out);
    }
}